// Round 1
// baseline (648.509 us; speedup 1.0000x reference)
//
#include <hip/hip_runtime.h>
#include <cstdio>

#define HID 64
#define D 128            // 2*HID
#define NUM_REL 230
#define NUM_TS 365
#define NCOMB (NUM_REL*NUM_TS)   // 83950
#define SLOPE 0.2f

__device__ __forceinline__ float lrelu(float v){ return v >= 0.f ? v : SLOPE*v; }

// ---------------------------------------------------------------------------
// K1: relP[r] = rel_table[r] @ W_rt[0:64, :]   (230 x 128)
//     timP[t] = time_table[t] @ W_rt[64:128,:] (365 x 128)
// grid = 595 blocks x 128 threads, one output row per block
// ---------------------------------------------------------------------------
__global__ __launch_bounds__(128) void k_parts(
        const float* __restrict__ rel_table, const float* __restrict__ time_table,
        const float* __restrict__ W_rt,
        float* __restrict__ relP, float* __restrict__ timP)
{
    int b = blockIdx.x, j = threadIdx.x;
    const float* tbl; const float* Wb; float* out;
    if (b < NUM_REL) { tbl = rel_table + b*HID;            Wb = W_rt;          out = relP + b*D; }
    else             { tbl = time_table + (b-NUM_REL)*HID; Wb = W_rt + HID*D;  out = timP + (b-NUM_REL)*D; }
    float acc = 0.f;
    #pragma unroll
    for (int k = 0; k < HID; ++k) acc += tbl[k] * Wb[k*D + j];
    out[j] = acc;
}

// ---------------------------------------------------------------------------
// K2: xW13[i, 0:128]   = x[i] @ W1   (W_fc rows 0..127)
//     xW13[i, 128:256] = x[i] @ W3   (W_fc rows 256..383)
// 256 threads: m = t>>7 selects W1/W3, j = t&127 is the output column.
// W column held in 128 VGPRs per thread; x row broadcast from LDS (b128).
// ---------------------------------------------------------------------------
__global__ __launch_bounds__(256) void k_xw(
        const float* __restrict__ x, const float* __restrict__ W_fc,
        float* __restrict__ xW13, int n_nodes)
{
    __shared__ __align__(16) float xbuf[D];
    int t = threadIdx.x;
    int m = t >> 7;          // 0 -> W1, 1 -> W3
    int j = t & 127;
    int base = (m == 0) ? 0 : 256;

    float Wreg[D];
    #pragma unroll
    for (int k = 0; k < D; ++k) Wreg[k] = W_fc[(base + k)*D + j];

    for (int i = blockIdx.x; i < n_nodes; i += gridDim.x) {
        if (t < D) xbuf[t] = x[(size_t)i*D + t];
        __syncthreads();
        float4 acc = make_float4(0.f, 0.f, 0.f, 0.f);
        const float4* xv4 = (const float4*)xbuf;
        #pragma unroll
        for (int kk = 0; kk < D/4; ++kk) {
            float4 xv = xv4[kk];
            acc.x += xv.x * Wreg[4*kk + 0];
            acc.y += xv.y * Wreg[4*kk + 1];
            acc.z += xv.z * Wreg[4*kk + 2];
            acc.w += xv.w * Wreg[4*kk + 3];
        }
        xW13[(size_t)i*256 + m*D + j] = (acc.x + acc.y) + (acc.z + acc.w);
        __syncthreads();
    }
}

// ---------------------------------------------------------------------------
// K3: for every (r,t) combo c: h = lrelu(relP[r] + timP[t] + b_rt)
//     T2[c] = h @ W2   (W_fc rows 128..255)
// 256 threads handle 2 combos per iteration (rl = t>>7), W2 column in VGPRs,
// h staged in LDS and broadcast via b128 reads.
// ---------------------------------------------------------------------------
__global__ __launch_bounds__(256) void k_t2(
        const float* __restrict__ relP, const float* __restrict__ timP,
        const float* __restrict__ b_rt, const float* __restrict__ W_fc,
        float* __restrict__ T2)
{
    __shared__ __align__(16) float h[2][D];
    int t = threadIdx.x;
    int rl = t >> 7;
    int j  = t & 127;

    float Wreg[D];
    #pragma unroll
    for (int k = 0; k < D; ++k) Wreg[k] = W_fc[(128 + k)*D + j];

    float brt = b_rt[j];

    for (int c0 = blockIdx.x*2; c0 < NCOMB; c0 += gridDim.x*2) {
        int cc = c0 + rl;                 // NCOMB even -> always valid
        int r  = cc / NUM_TS;
        int tt = cc - r*NUM_TS;
        h[rl][j] = lrelu(relP[r*D + j] + timP[tt*D + j] + brt);
        __syncthreads();
        float4 acc = make_float4(0.f, 0.f, 0.f, 0.f);
        const float4* hv4 = (const float4*)h[rl];
        #pragma unroll
        for (int kk = 0; kk < D/4; ++kk) {
            float4 hv = hv4[kk];
            acc.x += hv.x * Wreg[4*kk + 0];
            acc.y += hv.y * Wreg[4*kk + 1];
            acc.z += hv.z * Wreg[4*kk + 2];
            acc.w += hv.w * Wreg[4*kk + 3];
        }
        T2[(size_t)cc*D + j] = (acc.x + acc.y) + (acc.z + acc.w);
        __syncthreads();
    }
}

// ---------------------------------------------------------------------------
// K4: edge pass. 2 edges per 256-thread block.
// msg = lrelu(xW1[src] + T2[rel,ts] + xW3[dst] + b_fc); atomic scatter to out.
// ---------------------------------------------------------------------------
__global__ __launch_bounds__(256) void k_edge(
        const int* __restrict__ edges,
        const float* __restrict__ xW13, const float* __restrict__ T2,
        const float* __restrict__ b_fc,
        float* __restrict__ out, int* __restrict__ cnt, int n_edges)
{
    int t = threadIdx.x;
    int e = blockIdx.x*2 + (t >> 7);
    if (e >= n_edges) return;
    int j = t & 127;
    const int4 ed = ((const int4*)edges)[e];
    int src = ed.x, dst = ed.y, rel = ed.z, ts = ed.w;
    float v = xW13[(size_t)src*256 + j]
            + T2[(size_t)(rel*NUM_TS + ts)*D + j]
            + xW13[(size_t)dst*256 + D + j]
            + b_fc[j];
    atomicAdd(out + (size_t)dst*D + j, lrelu(v));
    if (j == 0) atomicAdd(cnt + dst, 1);
}

// ---------------------------------------------------------------------------
// K5: out[i][:] /= max(cnt[i], 1)
// ---------------------------------------------------------------------------
__global__ __launch_bounds__(256) void k_final(
        float* __restrict__ out, const int* __restrict__ cnt, int n_elems)
{
    int gid = blockIdx.x*256 + threadIdx.x;
    if (gid >= n_elems) return;
    float c = (float)cnt[gid >> 7];
    out[gid] = out[gid] / fmaxf(c, 1.0f);
}

// ---------------------------------------------------------------------------
extern "C" void kernel_launch(void* const* d_in, const int* in_sizes, int n_in,
                              void* d_out, int out_size, void* d_ws, size_t ws_size,
                              hipStream_t stream)
{
    const float* x          = (const float*)d_in[0];
    const float* rel_table  = (const float*)d_in[1];
    const float* time_table = (const float*)d_in[2];
    const float* W_rt       = (const float*)d_in[3];
    const float* b_rt       = (const float*)d_in[4];
    const float* W_fc       = (const float*)d_in[5];
    const float* b_fc       = (const float*)d_in[6];
    const int*   edges      = (const int*)d_in[7];

    int n_nodes = in_sizes[0] / D;   // 50000
    int n_edges = in_sizes[7] / 4;   // 400000

    char* ws = (char*)d_ws;
    size_t off = 0;
    auto alloc = [&](size_t bytes) -> void* {
        void* p = ws + off; off += (bytes + 255) & ~(size_t)255; return p;
    };
    float* xW13 = (float*)alloc((size_t)n_nodes * 256 * sizeof(float)); // 51.2 MB
    float* T2   = (float*)alloc((size_t)NCOMB * D * sizeof(float));     // 43.0 MB
    float* relP = (float*)alloc((size_t)NUM_REL * D * sizeof(float));
    float* timP = (float*)alloc((size_t)NUM_TS * D * sizeof(float));
    int*   cnt  = (int*)alloc((size_t)n_nodes * sizeof(int));
    if (off > ws_size)
        fprintf(stderr, "kernel_launch: workspace too small: need %zu, have %zu\n", off, ws_size);

    hipMemsetAsync(d_out, 0, (size_t)out_size * sizeof(float), stream);
    hipMemsetAsync(cnt, 0, (size_t)n_nodes * sizeof(int), stream);

    k_parts<<<NUM_REL + NUM_TS, 128, 0, stream>>>(rel_table, time_table, W_rt, relP, timP);
    k_xw   <<<1024, 256, 0, stream>>>(x, W_fc, xW13, n_nodes);
    k_t2   <<<1024, 256, 0, stream>>>(relP, timP, b_rt, W_fc, T2);
    k_edge <<<(n_edges + 1)/2, 256, 0, stream>>>(edges, xW13, T2, b_fc, (float*)d_out, cnt, n_edges);
    k_final<<<(n_nodes*D + 255)/256, 256, 0, stream>>>((float*)d_out, cnt, n_nodes*D);
}

// Round 2
// 402.502 us; speedup vs baseline: 1.6112x; 1.6112x over previous
//
#include <hip/hip_runtime.h>
#include <cstdio>

#define HID 64
#define D 128            // 2*HID
#define NUM_REL 230
#define NUM_TS 365
#define NCOMB (NUM_REL*NUM_TS)   // 83950
#define SLOPE 0.2f
#define BM 64
#define BK 32

__device__ __forceinline__ float lrelu(float v){ return v >= 0.f ? v : SLOPE*v; }

// ---------------------------------------------------------------------------
// K1: relP[r] = rel_table[r] @ W_rt[0:64, :]   (230 x 128)
//     timP[t] = time_table[t] @ W_rt[64:128,:] (365 x 128)
// ---------------------------------------------------------------------------
__global__ __launch_bounds__(128) void k_parts(
        const float* __restrict__ rel_table, const float* __restrict__ time_table,
        const float* __restrict__ W_rt,
        float* __restrict__ relP, float* __restrict__ timP)
{
    int b = blockIdx.x, j = threadIdx.x;
    const float* tbl; const float* Wb; float* out;
    if (b < NUM_REL) { tbl = rel_table + b*HID;            Wb = W_rt;          out = relP + b*D; }
    else             { tbl = time_table + (b-NUM_REL)*HID; Wb = W_rt + HID*D;  out = timP + (b-NUM_REL)*D; }
    float acc = 0.f;
    #pragma unroll
    for (int k = 0; k < HID; ++k) acc += tbl[k] * Wb[k*D + j];
    out[j] = acc;
}

// ---------------------------------------------------------------------------
// K2: xW13[M x 256] = x[M x 128] @ [W1 | W3]   (W_fc rows 0..127 and 256..383)
// LDS-tiled GEMM: block tile 64x256, Ktile=32, thread tile 8 rows x 8 cols.
// tx = t&31 -> cols tx+32*ci (bank = tx, conflict-free); ty = t>>5 -> rows ty*8.
// ---------------------------------------------------------------------------
__global__ __launch_bounds__(256) void k_xw(
        const float* __restrict__ x, const float* __restrict__ W_fc,
        float* __restrict__ xW13, int n_nodes)
{
    __shared__ __align__(16) float XsT[BK][BM];   // 8 KB, A-tile transposed
    __shared__ __align__(16) float Ws[BK][256];   // 32 KB
    int t  = threadIdx.x;
    int tx = t & 31;
    int ty = t >> 5;
    int rowBase = blockIdx.x * BM;

    float acc[8][8];
    #pragma unroll
    for (int i = 0; i < 8; ++i)
        #pragma unroll
        for (int j = 0; j < 8; ++j) acc[i][j] = 0.f;

    for (int kt = 0; kt < D; kt += BK) {
        // stage X^T: 64 rows x 32 k = 512 float4, 2 per thread
        #pragma unroll
        for (int q = 0; q < 2; ++q) {
            int u   = t*2 + q;
            int row = u >> 3;
            int k4  = u & 7;
            int grow = rowBase + row;
            float4 xv = make_float4(0.f,0.f,0.f,0.f);
            if (grow < n_nodes)
                xv = *(const float4*)&x[(size_t)grow*D + kt + k4*4];
            XsT[k4*4+0][row] = xv.x;
            XsT[k4*4+1][row] = xv.y;
            XsT[k4*4+2][row] = xv.z;
            XsT[k4*4+3][row] = xv.w;
        }
        // stage W: 32 k-rows x 256 cols = 2048 float4, 8 per thread
        #pragma unroll
        for (int q = 0; q < 8; ++q) {
            int u  = t + 256*q;
            int kk = u >> 6;          // 0..31
            int c  = (u & 63) * 4;    // 0..252
            int srcRow = (c < D) ? (kt + kk) : (256 + kt + kk);
            int srcCol = c & (D-1);
            *(float4*)&Ws[kk][c] = *(const float4*)&W_fc[(size_t)srcRow*D + srcCol];
        }
        __syncthreads();
        #pragma unroll 4
        for (int kk = 0; kk < BK; ++kk) {
            float xr[8];
            *(float4*)&xr[0] = *(const float4*)&XsT[kk][ty*8];
            *(float4*)&xr[4] = *(const float4*)&XsT[kk][ty*8+4];
            float wr[8];
            #pragma unroll
            for (int ci = 0; ci < 8; ++ci) wr[ci] = Ws[kk][tx + 32*ci];
            #pragma unroll
            for (int i = 0; i < 8; ++i)
                #pragma unroll
                for (int ci = 0; ci < 8; ++ci)
                    acc[i][ci] += xr[i]*wr[ci];
        }
        __syncthreads();
    }
    #pragma unroll
    for (int i = 0; i < 8; ++i) {
        int grow = rowBase + ty*8 + i;
        if (grow >= n_nodes) break;
        float* dst = xW13 + (size_t)grow*256;
        #pragma unroll
        for (int ci = 0; ci < 8; ++ci) dst[tx + 32*ci] = acc[i][ci];
    }
}

// ---------------------------------------------------------------------------
// K3: T2[c] = lrelu(relP[r]+timP[t]+b_rt) @ W2  (W_fc rows 128..255), c=(r,t)
// Same tiling: block 64x128, Ktile=32, thread tile 8 rows x 4 cols.
// H-tile generated on the fly into LDS.
// ---------------------------------------------------------------------------
__global__ __launch_bounds__(256) void k_t2(
        const float* __restrict__ relP, const float* __restrict__ timP,
        const float* __restrict__ b_rt, const float* __restrict__ W_fc,
        float* __restrict__ T2)
{
    __shared__ __align__(16) float HsT[BK][BM];   // 8 KB
    __shared__ __align__(16) float Ws[BK][D];     // 16 KB
    __shared__ int rrA[BM], ttA[BM];
    int t  = threadIdx.x;
    int tx = t & 31;
    int ty = t >> 5;
    int cBase = blockIdx.x * BM;

    if (t < BM) {
        int c = cBase + t;
        if (c >= NCOMB) c = NCOMB - 1;
        int rr = c / NUM_TS;
        rrA[t] = rr;
        ttA[t] = c - rr*NUM_TS;
    }

    float acc[8][4];
    #pragma unroll
    for (int i = 0; i < 8; ++i)
        #pragma unroll
        for (int j = 0; j < 4; ++j) acc[i][j] = 0.f;
    __syncthreads();

    for (int kt = 0; kt < D; kt += BK) {
        // stage H^T: 64 rows x 32 k, computed on the fly
        #pragma unroll
        for (int q = 0; q < 2; ++q) {
            int u   = t*2 + q;
            int row = u >> 3;
            int k   = kt + (u & 7)*4;
            int rr = rrA[row], tt = ttA[row];
            float4 rv = *(const float4*)&relP[(size_t)rr*D + k];
            float4 tv = *(const float4*)&timP[(size_t)tt*D + k];
            float4 bv = *(const float4*)&b_rt[k];
            HsT[(k-kt)+0][row] = lrelu(rv.x + tv.x + bv.x);
            HsT[(k-kt)+1][row] = lrelu(rv.y + tv.y + bv.y);
            HsT[(k-kt)+2][row] = lrelu(rv.z + tv.z + bv.z);
            HsT[(k-kt)+3][row] = lrelu(rv.w + tv.w + bv.w);
        }
        // stage W2 tile: 32 x 128 = 1024 float4, 4 per thread
        #pragma unroll
        for (int q = 0; q < 4; ++q) {
            int u  = t + 256*q;
            int kk = u >> 5;
            int c  = (u & 31) * 4;
            *(float4*)&Ws[kk][c] = *(const float4*)&W_fc[(size_t)(D + kt + kk)*D + c];
        }
        __syncthreads();
        #pragma unroll 4
        for (int kk = 0; kk < BK; ++kk) {
            float hr[8];
            *(float4*)&hr[0] = *(const float4*)&HsT[kk][ty*8];
            *(float4*)&hr[4] = *(const float4*)&HsT[kk][ty*8+4];
            float wr[4];
            #pragma unroll
            for (int ci = 0; ci < 4; ++ci) wr[ci] = Ws[kk][tx + 32*ci];
            #pragma unroll
            for (int i = 0; i < 8; ++i)
                #pragma unroll
                for (int ci = 0; ci < 4; ++ci)
                    acc[i][ci] += hr[i]*wr[ci];
        }
        __syncthreads();
    }
    #pragma unroll
    for (int i = 0; i < 8; ++i) {
        int c = cBase + ty*8 + i;
        if (c >= NCOMB) break;
        float* dst = T2 + (size_t)c*D;
        #pragma unroll
        for (int ci = 0; ci < 4; ++ci) dst[tx + 32*ci] = acc[i][ci];
    }
}

// ---------------------------------------------------------------------------
// K4: edge pass. 2 edges per 256-thread block, atomic scatter to out.
// ---------------------------------------------------------------------------
__global__ __launch_bounds__(256) void k_edge(
        const int* __restrict__ edges,
        const float* __restrict__ xW13, const float* __restrict__ T2,
        const float* __restrict__ b_fc,
        float* __restrict__ out, int* __restrict__ cnt, int n_edges)
{
    int t = threadIdx.x;
    int e = blockIdx.x*2 + (t >> 7);
    if (e >= n_edges) return;
    int j = t & 127;
    const int4 ed = ((const int4*)edges)[e];
    int src = ed.x, dst = ed.y, rel = ed.z, ts = ed.w;
    float v = xW13[(size_t)src*256 + j]
            + T2[(size_t)(rel*NUM_TS + ts)*D + j]
            + xW13[(size_t)dst*256 + D + j]
            + b_fc[j];
    atomicAdd(out + (size_t)dst*D + j, lrelu(v));
    if (j == 0) atomicAdd(cnt + dst, 1);
}

// ---------------------------------------------------------------------------
// K5: out[i][:] /= max(cnt[i], 1)
// ---------------------------------------------------------------------------
__global__ __launch_bounds__(256) void k_final(
        float* __restrict__ out, const int* __restrict__ cnt, int n_elems)
{
    int gid = blockIdx.x*256 + threadIdx.x;
    if (gid >= n_elems) return;
    float c = (float)cnt[gid >> 7];
    out[gid] = out[gid] / fmaxf(c, 1.0f);
}

// ---------------------------------------------------------------------------
extern "C" void kernel_launch(void* const* d_in, const int* in_sizes, int n_in,
                              void* d_out, int out_size, void* d_ws, size_t ws_size,
                              hipStream_t stream)
{
    const float* x          = (const float*)d_in[0];
    const float* rel_table  = (const float*)d_in[1];
    const float* time_table = (const float*)d_in[2];
    const float* W_rt       = (const float*)d_in[3];
    const float* b_rt       = (const float*)d_in[4];
    const float* W_fc       = (const float*)d_in[5];
    const float* b_fc       = (const float*)d_in[6];
    const int*   edges      = (const int*)d_in[7];

    int n_nodes = in_sizes[0] / D;   // 50000
    int n_edges = in_sizes[7] / 4;   // 400000

    char* ws = (char*)d_ws;
    size_t off = 0;
    auto alloc = [&](size_t bytes) -> void* {
        void* p = ws + off; off += (bytes + 255) & ~(size_t)255; return p;
    };
    float* xW13 = (float*)alloc((size_t)n_nodes * 256 * sizeof(float)); // 51.2 MB
    float* T2   = (float*)alloc((size_t)NCOMB * D * sizeof(float));     // 43.0 MB
    float* relP = (float*)alloc((size_t)NUM_REL * D * sizeof(float));
    float* timP = (float*)alloc((size_t)NUM_TS * D * sizeof(float));
    int*   cnt  = (int*)alloc((size_t)n_nodes * sizeof(int));
    if (off > ws_size)
        fprintf(stderr, "kernel_launch: workspace too small: need %zu, have %zu\n", off, ws_size);

    hipMemsetAsync(d_out, 0, (size_t)out_size * sizeof(float), stream);
    hipMemsetAsync(cnt, 0, (size_t)n_nodes * sizeof(int), stream);

    k_parts<<<NUM_REL + NUM_TS, 128, 0, stream>>>(rel_table, time_table, W_rt, relP, timP);
    k_xw   <<<(n_nodes + BM - 1)/BM, 256, 0, stream>>>(x, W_fc, xW13, n_nodes);
    k_t2   <<<(NCOMB + BM - 1)/BM, 256, 0, stream>>>(relP, timP, b_rt, W_fc, T2);
    k_edge <<<(n_edges + 1)/2, 256, 0, stream>>>(edges, xW13, T2, b_fc, (float*)d_out, cnt, n_edges);
    k_final<<<(n_nodes*D + 255)/256, 256, 0, stream>>>((float*)d_out, cnt, n_nodes*D);
}

// Round 3
// 295.122 us; speedup vs baseline: 2.1974x; 1.3638x over previous
//
#include <hip/hip_runtime.h>
#include <cstdio>

#define HID 64
#define D 128            // 2*HID
#define NUM_REL 230
#define NUM_TS 365
#define NCOMB (NUM_REL*NUM_TS)   // 83950
#define SLOPE 0.2f
#define BM 64
#define BK 32

__device__ __forceinline__ float lrelu(float v){ return v >= 0.f ? v : SLOPE*v; }

// bf16 helpers: pack two fp32 -> bf16x2 (RNE), unpack halves of a bf16x2 word
__device__ __forceinline__ unsigned bf_rne(float f){
    unsigned u = __float_as_uint(f);
    return (u + 0x7fffu + ((u >> 16) & 1u)) >> 16;
}
__device__ __forceinline__ unsigned pk2(float a, float b){
    return bf_rne(a) | (bf_rne(b) << 16);
}
__device__ __forceinline__ float bf_lo(unsigned u){ return __uint_as_float(u << 16); }
__device__ __forceinline__ float bf_hi(unsigned u){ return __uint_as_float(u & 0xffff0000u); }

// ---------------------------------------------------------------------------
// K1: relP[r] = rel_table[r] @ W_rt[0:64, :]   (230 x 128)
//     timP[t] = time_table[t] @ W_rt[64:128,:] (365 x 128)
// ---------------------------------------------------------------------------
__global__ __launch_bounds__(128) void k_parts(
        const float* __restrict__ rel_table, const float* __restrict__ time_table,
        const float* __restrict__ W_rt,
        float* __restrict__ relP, float* __restrict__ timP)
{
    int b = blockIdx.x, j = threadIdx.x;
    const float* tbl; const float* Wb; float* out;
    if (b < NUM_REL) { tbl = rel_table + b*HID;            Wb = W_rt;          out = relP + b*D; }
    else             { tbl = time_table + (b-NUM_REL)*HID; Wb = W_rt + HID*D;  out = timP + (b-NUM_REL)*D; }
    float acc = 0.f;
    #pragma unroll
    for (int k = 0; k < HID; ++k) acc += tbl[k] * Wb[k*D + j];
    out[j] = acc;
}

// ---------------------------------------------------------------------------
// K2: xW13bf[M x 256] = bf16( x[M x 128] @ [W1 | W3] )
// Block tile 64x256, Ktile=32, thread tile 8 rows x (4+4) cols at c=4*tx and
// 128+4*tx -> W read as 2x b128, X broadcast as 2x b128: 4 LDS instr / kk.
// ---------------------------------------------------------------------------
__global__ __launch_bounds__(256) void k_xw(
        const float* __restrict__ x, const float* __restrict__ W_fc,
        unsigned short* __restrict__ xW13bf, int n_nodes)
{
    __shared__ __align__(16) float XsT[BK][BM];   // 8 KB, A-tile transposed
    __shared__ __align__(16) float Ws[BK][256];   // 32 KB
    int t  = threadIdx.x;
    int tx = t & 31;
    int ty = t >> 5;
    int rowBase = blockIdx.x * BM;

    float acc[8][8];
    #pragma unroll
    for (int i = 0; i < 8; ++i)
        #pragma unroll
        for (int j = 0; j < 8; ++j) acc[i][j] = 0.f;

    for (int kt = 0; kt < D; kt += BK) {
        #pragma unroll
        for (int q = 0; q < 2; ++q) {
            int u   = t*2 + q;
            int row = u >> 3;
            int k4  = u & 7;
            int grow = rowBase + row;
            float4 xv = make_float4(0.f,0.f,0.f,0.f);
            if (grow < n_nodes)
                xv = *(const float4*)&x[(size_t)grow*D + kt + k4*4];
            XsT[k4*4+0][row] = xv.x;
            XsT[k4*4+1][row] = xv.y;
            XsT[k4*4+2][row] = xv.z;
            XsT[k4*4+3][row] = xv.w;
        }
        #pragma unroll
        for (int q = 0; q < 8; ++q) {
            int u  = t + 256*q;
            int kk = u >> 6;          // 0..31
            int c  = (u & 63) * 4;    // 0..252
            int srcRow = (c < D) ? (kt + kk) : (256 + kt + kk);
            int srcCol = c & (D-1);
            *(float4*)&Ws[kk][c] = *(const float4*)&W_fc[(size_t)srcRow*D + srcCol];
        }
        __syncthreads();
        #pragma unroll 4
        for (int kk = 0; kk < BK; ++kk) {
            float xr[8];
            *(float4*)&xr[0] = *(const float4*)&XsT[kk][ty*8];
            *(float4*)&xr[4] = *(const float4*)&XsT[kk][ty*8+4];
            const float4* w4 = (const float4*)&Ws[kk][0];
            float4 w0 = w4[tx];
            float4 w1 = w4[32 + tx];
            #pragma unroll
            for (int i = 0; i < 8; ++i) {
                acc[i][0] += xr[i]*w0.x; acc[i][1] += xr[i]*w0.y;
                acc[i][2] += xr[i]*w0.z; acc[i][3] += xr[i]*w0.w;
                acc[i][4] += xr[i]*w1.x; acc[i][5] += xr[i]*w1.y;
                acc[i][6] += xr[i]*w1.z; acc[i][7] += xr[i]*w1.w;
            }
        }
        __syncthreads();
    }
    #pragma unroll
    for (int i = 0; i < 8; ++i) {
        int grow = rowBase + ty*8 + i;
        if (grow >= n_nodes) break;
        uint2 p0 = make_uint2(pk2(acc[i][0], acc[i][1]), pk2(acc[i][2], acc[i][3]));
        uint2 p1 = make_uint2(pk2(acc[i][4], acc[i][5]), pk2(acc[i][6], acc[i][7]));
        *(uint2*)&xW13bf[(size_t)grow*256 + 4*tx]       = p0;  // W1 cols 4tx..
        *(uint2*)&xW13bf[(size_t)grow*256 + 128 + 4*tx] = p1;  // W3 cols 4tx..
    }
}

// ---------------------------------------------------------------------------
// K3: T2bf[c] = bf16( lrelu(relP[r]+timP[t]+b_rt) @ W2 ), c = r*NUM_TS+t
// Block tile 64x128, thread tile 8 rows x 4 cols at c=4*tx.
// ---------------------------------------------------------------------------
__global__ __launch_bounds__(256) void k_t2(
        const float* __restrict__ relP, const float* __restrict__ timP,
        const float* __restrict__ b_rt, const float* __restrict__ W_fc,
        unsigned short* __restrict__ T2bf)
{
    __shared__ __align__(16) float HsT[BK][BM];   // 8 KB
    __shared__ __align__(16) float Ws[BK][D];     // 16 KB
    __shared__ int rrA[BM], ttA[BM];
    int t  = threadIdx.x;
    int tx = t & 31;
    int ty = t >> 5;
    int cBase = blockIdx.x * BM;

    if (t < BM) {
        int c = cBase + t;
        if (c >= NCOMB) c = NCOMB - 1;
        int rr = c / NUM_TS;
        rrA[t] = rr;
        ttA[t] = c - rr*NUM_TS;
    }

    float acc[8][4];
    #pragma unroll
    for (int i = 0; i < 8; ++i)
        #pragma unroll
        for (int j = 0; j < 4; ++j) acc[i][j] = 0.f;
    __syncthreads();

    for (int kt = 0; kt < D; kt += BK) {
        #pragma unroll
        for (int q = 0; q < 2; ++q) {
            int u   = t*2 + q;
            int row = u >> 3;
            int k   = kt + (u & 7)*4;
            int rr = rrA[row], tt = ttA[row];
            float4 rv = *(const float4*)&relP[(size_t)rr*D + k];
            float4 tv = *(const float4*)&timP[(size_t)tt*D + k];
            float4 bv = *(const float4*)&b_rt[k];
            HsT[(k-kt)+0][row] = lrelu(rv.x + tv.x + bv.x);
            HsT[(k-kt)+1][row] = lrelu(rv.y + tv.y + bv.y);
            HsT[(k-kt)+2][row] = lrelu(rv.z + tv.z + bv.z);
            HsT[(k-kt)+3][row] = lrelu(rv.w + tv.w + bv.w);
        }
        #pragma unroll
        for (int q = 0; q < 4; ++q) {
            int u  = t + 256*q;
            int kk = u >> 5;
            int c  = (u & 31) * 4;
            *(float4*)&Ws[kk][c] = *(const float4*)&W_fc[(size_t)(D + kt + kk)*D + c];
        }
        __syncthreads();
        #pragma unroll 4
        for (int kk = 0; kk < BK; ++kk) {
            float hr[8];
            *(float4*)&hr[0] = *(const float4*)&HsT[kk][ty*8];
            *(float4*)&hr[4] = *(const float4*)&HsT[kk][ty*8+4];
            float4 w = ((const float4*)&Ws[kk][0])[tx];
            #pragma unroll
            for (int i = 0; i < 8; ++i) {
                acc[i][0] += hr[i]*w.x; acc[i][1] += hr[i]*w.y;
                acc[i][2] += hr[i]*w.z; acc[i][3] += hr[i]*w.w;
            }
        }
        __syncthreads();
    }
    #pragma unroll
    for (int i = 0; i < 8; ++i) {
        int c = cBase + ty*8 + i;
        if (c >= NCOMB) break;
        uint2 p = make_uint2(pk2(acc[i][0], acc[i][1]), pk2(acc[i][2], acc[i][3]));
        *(uint2*)&T2bf[(size_t)c*D + 4*tx] = p;
    }
}

// ---------------------------------------------------------------------------
// CSR build: degree count -> block scan -> scatter {src, combo} per dst.
// ---------------------------------------------------------------------------
__global__ __launch_bounds__(256) void k_count(
        const int* __restrict__ edges, int* __restrict__ deg, int n_edges)
{
    int e = blockIdx.x*256 + threadIdx.x;
    if (e >= n_edges) return;
    atomicAdd(&deg[((const int4*)edges)[e].y], 1);
}

__global__ __launch_bounds__(256) void k_scan1(
        const int* __restrict__ deg, int* __restrict__ inc,
        int* __restrict__ blkSum, int n)
{
    __shared__ int s[256];
    int i = blockIdx.x*256 + threadIdx.x;
    s[threadIdx.x] = (i < n) ? deg[i] : 0;
    __syncthreads();
    #pragma unroll
    for (int off = 1; off < 256; off <<= 1) {
        int v = (threadIdx.x >= off) ? s[threadIdx.x - off] : 0;
        __syncthreads();
        s[threadIdx.x] += v;
        __syncthreads();
    }
    if (i < n) inc[i] = s[threadIdx.x];
    if (threadIdx.x == 255) blkSum[blockIdx.x] = s[255];
}

__global__ __launch_bounds__(256) void k_scan2(int* __restrict__ blkSum, int nblk)
{
    __shared__ int s[256];
    s[threadIdx.x] = (threadIdx.x < nblk) ? blkSum[threadIdx.x] : 0;
    __syncthreads();
    #pragma unroll
    for (int off = 1; off < 256; off <<= 1) {
        int v = (threadIdx.x >= off) ? s[threadIdx.x - off] : 0;
        __syncthreads();
        s[threadIdx.x] += v;
        __syncthreads();
    }
    if (threadIdx.x < nblk) blkSum[threadIdx.x] = s[threadIdx.x];
}

__global__ __launch_bounds__(256) void k_scan3(
        const int* __restrict__ inc, const int* __restrict__ blkSum,
        const int* __restrict__ deg, int* __restrict__ rowPtr,
        int* __restrict__ wIdx, int n)
{
    int i = blockIdx.x*256 + threadIdx.x;
    if (i >= n) return;
    int carry = (blockIdx.x > 0) ? blkSum[blockIdx.x - 1] : 0;
    int incl = inc[i] + carry;
    rowPtr[i+1] = incl;
    wIdx[i] = incl - deg[i];
    if (i == 0) rowPtr[0] = 0;
}

__global__ __launch_bounds__(256) void k_scatter(
        const int* __restrict__ edges, int* __restrict__ wIdx,
        int2* __restrict__ ebuf, int n_edges)
{
    int e = blockIdx.x*256 + threadIdx.x;
    if (e >= n_edges) return;
    int4 ed = ((const int4*)edges)[e];
    int p = atomicAdd(&wIdx[ed.y], 1);
    ebuf[p] = make_int2(ed.x, ed.z*NUM_TS + ed.w);
}

// ---------------------------------------------------------------------------
// K4: aggregation. One wave per dst node, 2 cols per lane (bf16x2 gathers).
// out[dst] = mean_e lrelu(xW1[src_e] + T2[c_e] + xW3[dst] + b_fc)
// ---------------------------------------------------------------------------
__global__ __launch_bounds__(256) void k_agg(
        const int* __restrict__ rowPtr, const int2* __restrict__ ebuf,
        const unsigned short* __restrict__ xW13bf,
        const unsigned short* __restrict__ T2bf,
        const float* __restrict__ b_fc,
        float* __restrict__ out, int n_nodes)
{
    int node = blockIdx.x*4 + (threadIdx.x >> 6);
    int lane = threadIdx.x & 63;
    if (node >= n_nodes) return;
    int beg = rowPtr[node], end = rowPtr[node+1];

    float2 bb = *(const float2*)&b_fc[2*lane];
    unsigned xw3 = *(const unsigned*)&xW13bf[(size_t)node*256 + 128 + 2*lane];
    float base0 = bf_lo(xw3) + bb.x;
    float base1 = bf_hi(xw3) + bb.y;

    float a0 = 0.f, a1 = 0.f;
    for (int e = beg; e < end; ++e) {
        int2 ed = ebuf[e];
        unsigned u1 = *(const unsigned*)&xW13bf[(size_t)ed.x*256 + 2*lane];
        unsigned u2 = *(const unsigned*)&T2bf[(size_t)ed.y*D + 2*lane];
        float v0 = bf_lo(u1) + bf_lo(u2) + base0;
        float v1 = bf_hi(u1) + bf_hi(u2) + base1;
        a0 += lrelu(v0);
        a1 += lrelu(v1);
    }
    float inv = 1.f / fmaxf((float)(end - beg), 1.f);
    *(float2*)&out[(size_t)node*D + 2*lane] = make_float2(a0*inv, a1*inv);
}

// ---------------------------------------------------------------------------
extern "C" void kernel_launch(void* const* d_in, const int* in_sizes, int n_in,
                              void* d_out, int out_size, void* d_ws, size_t ws_size,
                              hipStream_t stream)
{
    const float* x          = (const float*)d_in[0];
    const float* rel_table  = (const float*)d_in[1];
    const float* time_table = (const float*)d_in[2];
    const float* W_rt       = (const float*)d_in[3];
    const float* b_rt       = (const float*)d_in[4];
    const float* W_fc       = (const float*)d_in[5];
    const float* b_fc       = (const float*)d_in[6];
    const int*   edges      = (const int*)d_in[7];

    int n_nodes = in_sizes[0] / D;   // 50000
    int n_edges = in_sizes[7] / 4;   // 400000
    int nblk    = (n_nodes + 255) / 256;

    char* ws = (char*)d_ws;
    size_t off = 0;
    auto alloc = [&](size_t bytes) -> void* {
        void* p = ws + off; off += (bytes + 255) & ~(size_t)255; return p;
    };
    unsigned short* xW13bf = (unsigned short*)alloc((size_t)n_nodes * 256 * 2); // 25.6 MB
    unsigned short* T2bf   = (unsigned short*)alloc((size_t)NCOMB * D * 2);     // 21.5 MB
    float* relP   = (float*)alloc((size_t)NUM_REL * D * sizeof(float));
    float* timP   = (float*)alloc((size_t)NUM_TS * D * sizeof(float));
    int*   deg    = (int*)alloc((size_t)n_nodes * sizeof(int));
    int*   inc    = (int*)alloc((size_t)n_nodes * sizeof(int));
    int*   blkSum = (int*)alloc((size_t)nblk * sizeof(int));
    int*   rowPtr = (int*)alloc((size_t)(n_nodes + 1) * sizeof(int));
    int*   wIdx   = (int*)alloc((size_t)n_nodes * sizeof(int));
    int2*  ebuf   = (int2*)alloc((size_t)n_edges * sizeof(int2));               // 3.2 MB
    if (off > ws_size)
        fprintf(stderr, "kernel_launch: workspace too small: need %zu, have %zu\n", off, ws_size);

    hipMemsetAsync(deg, 0, (size_t)n_nodes * sizeof(int), stream);

    k_parts  <<<NUM_REL + NUM_TS, 128, 0, stream>>>(rel_table, time_table, W_rt, relP, timP);
    k_xw     <<<(n_nodes + BM - 1)/BM, 256, 0, stream>>>(x, W_fc, xW13bf, n_nodes);
    k_t2     <<<(NCOMB + BM - 1)/BM, 256, 0, stream>>>(relP, timP, b_rt, W_fc, T2bf);
    k_count  <<<(n_edges + 255)/256, 256, 0, stream>>>(edges, deg, n_edges);
    k_scan1  <<<nblk, 256, 0, stream>>>(deg, inc, blkSum, n_nodes);
    k_scan2  <<<1, 256, 0, stream>>>(blkSum, nblk);
    k_scan3  <<<nblk, 256, 0, stream>>>(inc, blkSum, deg, rowPtr, wIdx, n_nodes);
    k_scatter<<<(n_edges + 255)/256, 256, 0, stream>>>(edges, wIdx, ebuf, n_edges);
    k_agg    <<<(n_nodes + 3)/4, 256, 0, stream>>>(rowPtr, ebuf, xW13bf, T2bf, b_fc,
                                                   (float*)d_out, n_nodes);
}

// Round 4
// 237.163 us; speedup vs baseline: 2.7344x; 1.2444x over previous
//
#include <hip/hip_runtime.h>
#include <cstdio>

#define HID 64
#define D 128            // 2*HID
#define NUM_REL 230
#define NUM_TS 365
#define NCOMB (NUM_REL*NUM_TS)   // 83950
#define SLOPE 0.2f
#define XPAD 136         // LDS row stride in bf16 (272 B -> 2-way bank alias, free)

typedef __attribute__((ext_vector_type(8))) short short8;
typedef __attribute__((ext_vector_type(4))) float f32x4;

__device__ __forceinline__ float lrelu(float v){ return v >= 0.f ? v : SLOPE*v; }

// bf16 helpers
__device__ __forceinline__ unsigned bf_rne(float f){
    unsigned u = __float_as_uint(f);
    return (u + 0x7fffu + ((u >> 16) & 1u)) >> 16;
}
__device__ __forceinline__ unsigned pk2(float a, float b){
    return bf_rne(a) | (bf_rne(b) << 16);
}
__device__ __forceinline__ float bf_lo(unsigned u){ return __uint_as_float(u << 16); }
__device__ __forceinline__ float bf_hi(unsigned u){ return __uint_as_float(u & 0xffff0000u); }

// ---------------------------------------------------------------------------
// K1: relP[r] = rel_table[r] @ W_rt[0:64, :]   (230 x 128, fp32)
//     timP[t] = time_table[t] @ W_rt[64:128,:] (365 x 128, fp32)
// ---------------------------------------------------------------------------
__global__ __launch_bounds__(128) void k_parts(
        const float* __restrict__ rel_table, const float* __restrict__ time_table,
        const float* __restrict__ W_rt,
        float* __restrict__ relP, float* __restrict__ timP)
{
    int b = blockIdx.x, j = threadIdx.x;
    const float* tbl; const float* Wb; float* out;
    if (b < NUM_REL) { tbl = rel_table + b*HID;            Wb = W_rt;          out = relP + b*D; }
    else             { tbl = time_table + (b-NUM_REL)*HID; Wb = W_rt + HID*D;  out = timP + (b-NUM_REL)*D; }
    float acc = 0.f;
    #pragma unroll
    for (int k = 0; k < HID; ++k) acc += tbl[k] * Wb[k*D + j];
    out[j] = acc;
}

// ---------------------------------------------------------------------------
// k_wpack: pre-pack W13^T (=[W1|W3] cols as rows) and W2^T into MFMA A-frag
// order, bf16. Frag-lane id -> 8 k-consecutive elements.
// W13: 16 mtiles x 4 ksteps; W2: 8 mtiles x 4 ksteps.
// Layout: Wpk[( mt*4 + s )*64 + lane][8]  (dwordx4-coalesced frag loads)
// ---------------------------------------------------------------------------
__global__ __launch_bounds__(256) void k_wpack(
        const float* __restrict__ W_fc,
        unsigned short* __restrict__ Wpk13, unsigned short* __restrict__ Wpk2)
{
    int id = blockIdx.x*256 + threadIdx.x;
    if (id < 4096) {                 // W13 frags
        int mt = id >> 8;            // 0..15
        int s  = (id >> 6) & 3;
        int l  = id & 63;
        int m  = mt*16 + (l & 15);   // output col 0..255
        int kb = s*32 + (l >> 4)*8;
        unsigned short* dst = Wpk13 + ((size_t)(mt*4 + s)*64 + l)*8;
        #pragma unroll
        for (int j = 0; j < 8; ++j) {
            int k = kb + j;
            float v = (m < D) ? W_fc[(size_t)k*D + m]
                              : W_fc[(size_t)(256 + k)*D + (m - D)];
            dst[j] = (unsigned short)bf_rne(v);
        }
    } else if (id < 6144) {          // W2 frags
        int id2 = id - 4096;
        int mt = id2 >> 8;           // 0..7
        int s  = (id2 >> 6) & 3;
        int l  = id2 & 63;
        int m  = mt*16 + (l & 15);
        int kb = s*32 + (l >> 4)*8;
        unsigned short* dst = Wpk2 + ((size_t)(mt*4 + s)*64 + l)*8;
        #pragma unroll
        for (int j = 0; j < 8; ++j) {
            int k = kb + j;
            dst[j] = (unsigned short)bf_rne(W_fc[(size_t)(D + k)*D + m]);
        }
    }
}

// ---------------------------------------------------------------------------
// K2 (MFMA): xW13bf[node][256] = bf16( x[node] @ [W1|W3] ), computed as C^T.
// Block: 64 nodes x 256 cols, 4 waves (wave w -> cols w*64..w*64+63).
// A = W13^T frags from Wpk13 (global, L2-hot); B = X tile bf16 in LDS.
// ---------------------------------------------------------------------------
__global__ __launch_bounds__(256, 3) void k_xw(
        const float* __restrict__ x, const unsigned short* __restrict__ Wpk13,
        unsigned short* __restrict__ xW13bf, int n_nodes)
{
    __shared__ __align__(16) unsigned short Xs[64*XPAD];   // 17.4 KB
    int t = threadIdx.x;
    int nodeBase = blockIdx.x*64;
    {   // stage X tile (fp32 -> bf16), 4 threads per node row
        int row = t >> 2;
        int k0  = (t & 3)*32;
        int node = nodeBase + row;
        unsigned short* dst = Xs + row*XPAD + k0;
        if (node < n_nodes) {
            const float4* src = (const float4*)(x + (size_t)node*D + k0);
            #pragma unroll
            for (int g = 0; g < 8; ++g) {
                float4 v = src[g];
                *(uint2*)(dst + g*4) = make_uint2(pk2(v.x, v.y), pk2(v.z, v.w));
            }
        } else {
            #pragma unroll
            for (int g = 0; g < 8; ++g)
                *(uint2*)(dst + g*4) = make_uint2(0u, 0u);
        }
    }
    __syncthreads();

    int w = t >> 6, l = t & 63;
    int li = l & 15, q = l >> 4;

    f32x4 acc[4][4];
    #pragma unroll
    for (int mi = 0; mi < 4; ++mi)
        #pragma unroll
        for (int ni = 0; ni < 4; ++ni) acc[mi][ni] = (f32x4){0.f,0.f,0.f,0.f};

    #pragma unroll
    for (int s = 0; s < 4; ++s) {
        short8 af[4], bf[4];
        #pragma unroll
        for (int mi = 0; mi < 4; ++mi) {
            int mt = w*4 + mi;
            af[mi] = *(const short8*)(Wpk13 + ((size_t)(mt*4 + s)*64 + l)*8);
        }
        #pragma unroll
        for (int ni = 0; ni < 4; ++ni)
            bf[ni] = *(const short8*)(Xs + (ni*16 + li)*XPAD + s*32 + q*8);
        #pragma unroll
        for (int mi = 0; mi < 4; ++mi)
            #pragma unroll
            for (int ni = 0; ni < 4; ++ni)
                acc[mi][ni] = __builtin_amdgcn_mfma_f32_16x16x32_bf16(
                                  af[mi], bf[ni], acc[mi][ni], 0, 0, 0);
    }
    // store: lane holds node = li (n-dim), 4 consecutive cols (m-dim) per acc
    #pragma unroll
    for (int ni = 0; ni < 4; ++ni) {
        int node = nodeBase + ni*16 + li;
        if (node >= n_nodes) continue;
        #pragma unroll
        for (int mi = 0; mi < 4; ++mi) {
            int col = w*64 + mi*16 + q*4;
            *(uint2*)(xW13bf + (size_t)node*256 + col) =
                make_uint2(pk2(acc[mi][ni][0], acc[mi][ni][1]),
                           pk2(acc[mi][ni][2], acc[mi][ni][3]));
        }
    }
}

// ---------------------------------------------------------------------------
// K3 (MFMA): T2bf[c][128] = bf16( lrelu(relP[r]+timP[t]+b_rt) @ W2 ), as C^T.
// Block: 128 combos x 128 cols, 4 waves in 2x2 (m x n) quadrants.
// ---------------------------------------------------------------------------
__global__ __launch_bounds__(256, 3) void k_t2(
        const float* __restrict__ relP, const float* __restrict__ timP,
        const float* __restrict__ b_rt, const unsigned short* __restrict__ Wpk2,
        unsigned short* __restrict__ T2bf)
{
    __shared__ __align__(16) unsigned short Hs[128*XPAD];  // 34.8 KB
    int t = threadIdx.x;
    int cBase = blockIdx.x*128;
    {   // stage H tile: compute lrelu(relP+timP+b) -> bf16, 2 threads per row
        int r  = t >> 1;
        int hk = (t & 1)*64;
        int combo = cBase + r;
        if (combo >= NCOMB) combo = NCOMB - 1;
        int rr = combo / NUM_TS;
        int tt = combo - rr*NUM_TS;
        const float4* rv4 = (const float4*)(relP + (size_t)rr*D + hk);
        const float4* tv4 = (const float4*)(timP + (size_t)tt*D + hk);
        const float4* bv4 = (const float4*)(b_rt + hk);
        unsigned short* dst = Hs + r*XPAD + hk;
        #pragma unroll
        for (int g = 0; g < 16; ++g) {
            float4 rv = rv4[g], tv = tv4[g], bv = bv4[g];
            float v0 = lrelu(rv.x+tv.x+bv.x), v1 = lrelu(rv.y+tv.y+bv.y);
            float v2 = lrelu(rv.z+tv.z+bv.z), v3 = lrelu(rv.w+tv.w+bv.w);
            *(uint2*)(dst + g*4) = make_uint2(pk2(v0,v1), pk2(v2,v3));
        }
    }
    __syncthreads();

    int w = t >> 6, l = t & 63;
    int li = l & 15, q = l >> 4;
    int mb = (w & 1)*4;        // m-tile base: cols (mb+mi)*16
    int nb = (w >> 1)*64;      // combo base within block

    f32x4 acc[4][4];
    #pragma unroll
    for (int mi = 0; mi < 4; ++mi)
        #pragma unroll
        for (int ni = 0; ni < 4; ++ni) acc[mi][ni] = (f32x4){0.f,0.f,0.f,0.f};

    #pragma unroll
    for (int s = 0; s < 4; ++s) {
        short8 af[4], bf[4];
        #pragma unroll
        for (int mi = 0; mi < 4; ++mi)
            af[mi] = *(const short8*)(Wpk2 + ((size_t)((mb+mi)*4 + s)*64 + l)*8);
        #pragma unroll
        for (int ni = 0; ni < 4; ++ni)
            bf[ni] = *(const short8*)(Hs + (nb + ni*16 + li)*XPAD + s*32 + q*8);
        #pragma unroll
        for (int mi = 0; mi < 4; ++mi)
            #pragma unroll
            for (int ni = 0; ni < 4; ++ni)
                acc[mi][ni] = __builtin_amdgcn_mfma_f32_16x16x32_bf16(
                                  af[mi], bf[ni], acc[mi][ni], 0, 0, 0);
    }
    #pragma unroll
    for (int ni = 0; ni < 4; ++ni) {
        int combo = cBase + nb + ni*16 + li;
        if (combo >= NCOMB) continue;
        #pragma unroll
        for (int mi = 0; mi < 4; ++mi) {
            int col = (mb + mi)*16 + q*4;
            *(uint2*)(T2bf + (size_t)combo*D + col) =
                make_uint2(pk2(acc[mi][ni][0], acc[mi][ni][1]),
                           pk2(acc[mi][ni][2], acc[mi][ni][3]));
        }
    }
}

// ---------------------------------------------------------------------------
// CSR build: degree count -> block scan -> scatter {src, combo} per dst.
// ---------------------------------------------------------------------------
__global__ __launch_bounds__(256) void k_count(
        const int* __restrict__ edges, int* __restrict__ deg, int n_edges)
{
    int e = blockIdx.x*256 + threadIdx.x;
    if (e >= n_edges) return;
    atomicAdd(&deg[((const int4*)edges)[e].y], 1);
}

__global__ __launch_bounds__(256) void k_scan1(
        const int* __restrict__ deg, int* __restrict__ inc,
        int* __restrict__ blkSum, int n)
{
    __shared__ int s[256];
    int i = blockIdx.x*256 + threadIdx.x;
    s[threadIdx.x] = (i < n) ? deg[i] : 0;
    __syncthreads();
    #pragma unroll
    for (int off = 1; off < 256; off <<= 1) {
        int v = (threadIdx.x >= off) ? s[threadIdx.x - off] : 0;
        __syncthreads();
        s[threadIdx.x] += v;
        __syncthreads();
    }
    if (i < n) inc[i] = s[threadIdx.x];
    if (threadIdx.x == 255) blkSum[blockIdx.x] = s[255];
}

__global__ __launch_bounds__(256) void k_scan2(int* __restrict__ blkSum, int nblk)
{
    __shared__ int s[256];
    s[threadIdx.x] = (threadIdx.x < nblk) ? blkSum[threadIdx.x] : 0;
    __syncthreads();
    #pragma unroll
    for (int off = 1; off < 256; off <<= 1) {
        int v = (threadIdx.x >= off) ? s[threadIdx.x - off] : 0;
        __syncthreads();
        s[threadIdx.x] += v;
        __syncthreads();
    }
    if (threadIdx.x < nblk) blkSum[threadIdx.x] = s[threadIdx.x];
}

__global__ __launch_bounds__(256) void k_scan3(
        const int* __restrict__ inc, const int* __restrict__ blkSum,
        const int* __restrict__ deg, int* __restrict__ rowPtr,
        int* __restrict__ wIdx, int n)
{
    int i = blockIdx.x*256 + threadIdx.x;
    if (i >= n) return;
    int carry = (blockIdx.x > 0) ? blkSum[blockIdx.x - 1] : 0;
    int incl = inc[i] + carry;
    rowPtr[i+1] = incl;
    wIdx[i] = incl - deg[i];
    if (i == 0) rowPtr[0] = 0;
}

__global__ __launch_bounds__(256) void k_scatter(
        const int* __restrict__ edges, int* __restrict__ wIdx,
        int2* __restrict__ ebuf, int n_edges)
{
    int e = blockIdx.x*256 + threadIdx.x;
    if (e >= n_edges) return;
    int4 ed = ((const int4*)edges)[e];
    int p = atomicAdd(&wIdx[ed.y], 1);
    ebuf[p] = make_int2(ed.x, ed.z*NUM_TS + ed.w);
}

// ---------------------------------------------------------------------------
// K4: aggregation. One wave per dst node, 2 cols per lane (bf16x2 gathers).
// ---------------------------------------------------------------------------
__global__ __launch_bounds__(256) void k_agg(
        const int* __restrict__ rowPtr, const int2* __restrict__ ebuf,
        const unsigned short* __restrict__ xW13bf,
        const unsigned short* __restrict__ T2bf,
        const float* __restrict__ b_fc,
        float* __restrict__ out, int n_nodes)
{
    int node = blockIdx.x*4 + (threadIdx.x >> 6);
    int lane = threadIdx.x & 63;
    if (node >= n_nodes) return;
    int beg = rowPtr[node], end = rowPtr[node+1];

    float2 bb = *(const float2*)&b_fc[2*lane];
    unsigned xw3 = *(const unsigned*)&xW13bf[(size_t)node*256 + 128 + 2*lane];
    float base0 = bf_lo(xw3) + bb.x;
    float base1 = bf_hi(xw3) + bb.y;

    float a0 = 0.f, a1 = 0.f;
    for (int e = beg; e < end; ++e) {
        int2 ed = ebuf[e];
        unsigned u1 = *(const unsigned*)&xW13bf[(size_t)ed.x*256 + 2*lane];
        unsigned u2 = *(const unsigned*)&T2bf[(size_t)ed.y*D + 2*lane];
        a0 += lrelu(bf_lo(u1) + bf_lo(u2) + base0);
        a1 += lrelu(bf_hi(u1) + bf_hi(u2) + base1);
    }
    float inv = 1.f / fmaxf((float)(end - beg), 1.f);
    *(float2*)&out[(size_t)node*D + 2*lane] = make_float2(a0*inv, a1*inv);
}

// ---------------------------------------------------------------------------
extern "C" void kernel_launch(void* const* d_in, const int* in_sizes, int n_in,
                              void* d_out, int out_size, void* d_ws, size_t ws_size,
                              hipStream_t stream)
{
    const float* x          = (const float*)d_in[0];
    const float* rel_table  = (const float*)d_in[1];
    const float* time_table = (const float*)d_in[2];
    const float* W_rt       = (const float*)d_in[3];
    const float* b_rt       = (const float*)d_in[4];
    const float* W_fc       = (const float*)d_in[5];
    const float* b_fc       = (const float*)d_in[6];
    const int*   edges      = (const int*)d_in[7];

    int n_nodes = in_sizes[0] / D;   // 50000
    int n_edges = in_sizes[7] / 4;   // 400000
    int nblk    = (n_nodes + 255) / 256;

    char* ws = (char*)d_ws;
    size_t off = 0;
    auto alloc = [&](size_t bytes) -> void* {
        void* p = ws + off; off += (bytes + 255) & ~(size_t)255; return p;
    };
    unsigned short* xW13bf = (unsigned short*)alloc((size_t)n_nodes * 256 * 2); // 25.6 MB
    unsigned short* T2bf   = (unsigned short*)alloc((size_t)NCOMB * D * 2);     // 21.5 MB
    unsigned short* Wpk13  = (unsigned short*)alloc((size_t)16*4*64*8 * 2);     // 64 KB
    unsigned short* Wpk2   = (unsigned short*)alloc((size_t)8*4*64*8 * 2);      // 32 KB
    float* relP   = (float*)alloc((size_t)NUM_REL * D * sizeof(float));
    float* timP   = (float*)alloc((size_t)NUM_TS * D * sizeof(float));
    int*   deg    = (int*)alloc((size_t)n_nodes * sizeof(int));
    int*   inc    = (int*)alloc((size_t)n_nodes * sizeof(int));
    int*   blkSum = (int*)alloc((size_t)nblk * sizeof(int));
    int*   rowPtr = (int*)alloc((size_t)(n_nodes + 1) * sizeof(int));
    int*   wIdx   = (int*)alloc((size_t)n_nodes * sizeof(int));
    int2*  ebuf   = (int2*)alloc((size_t)n_edges * sizeof(int2));               // 3.2 MB
    if (off > ws_size)
        fprintf(stderr, "kernel_launch: workspace too small: need %zu, have %zu\n", off, ws_size);

    hipMemsetAsync(deg, 0, (size_t)n_nodes * sizeof(int), stream);

    k_parts  <<<NUM_REL + NUM_TS, 128, 0, stream>>>(rel_table, time_table, W_rt, relP, timP);
    k_wpack  <<<24, 256, 0, stream>>>(W_fc, Wpk13, Wpk2);
    k_xw     <<<(n_nodes + 63)/64, 256, 0, stream>>>(x, Wpk13, xW13bf, n_nodes);
    k_t2     <<<(NCOMB + 127)/128, 256, 0, stream>>>(relP, timP, b_rt, Wpk2, T2bf);
    k_count  <<<(n_edges + 255)/256, 256, 0, stream>>>(edges, deg, n_edges);
    k_scan1  <<<nblk, 256, 0, stream>>>(deg, inc, blkSum, n_nodes);
    k_scan2  <<<1, 256, 0, stream>>>(blkSum, nblk);
    k_scan3  <<<nblk, 256, 0, stream>>>(inc, blkSum, deg, rowPtr, wIdx, n_nodes);
    k_scatter<<<(n_edges + 255)/256, 256, 0, stream>>>(edges, wIdx, ebuf, n_edges);
    k_agg    <<<(n_nodes + 3)/4, 256, 0, stream>>>(rowPtr, ebuf, xW13bf, T2bf, b_fc,
                                                   (float*)d_out, n_nodes);
}

// Round 5
// 212.534 us; speedup vs baseline: 3.0513x; 1.1159x over previous
//
#include <hip/hip_runtime.h>
#include <cstdio>

#define HID 64
#define D 128            // 2*HID
#define NUM_REL 230
#define NUM_TS 365
#define NCOMB (NUM_REL*NUM_TS)   // 83950
#define SLOPE 0.2f
#define XPAD 136         // LDS row stride in bf16 (272 B -> 2-way bank alias, free)

typedef __attribute__((ext_vector_type(8))) short short8;
typedef __attribute__((ext_vector_type(4))) float f32x4;

__device__ __forceinline__ float lrelu(float v){ return v >= 0.f ? v : SLOPE*v; }

// bf16 helpers
__device__ __forceinline__ unsigned bf_rne(float f){
    unsigned u = __float_as_uint(f);
    return (u + 0x7fffu + ((u >> 16) & 1u)) >> 16;
}
__device__ __forceinline__ unsigned pk2(float a, float b){
    return bf_rne(a) | (bf_rne(b) << 16);
}
__device__ __forceinline__ float bf_lo(unsigned u){ return __uint_as_float(u << 16); }
__device__ __forceinline__ float bf_hi(unsigned u){ return __uint_as_float(u & 0xffff0000u); }

// ---------------------------------------------------------------------------
// K1: relP[r] = rel_table[r] @ W_rt[0:64, :]   (230 x 128, fp32)
//     timP[t] = time_table[t] @ W_rt[64:128,:] (365 x 128, fp32)
// ---------------------------------------------------------------------------
__global__ __launch_bounds__(128) void k_parts(
        const float* __restrict__ rel_table, const float* __restrict__ time_table,
        const float* __restrict__ W_rt,
        float* __restrict__ relP, float* __restrict__ timP)
{
    int b = blockIdx.x, j = threadIdx.x;
    const float* tbl; const float* Wb; float* out;
    if (b < NUM_REL) { tbl = rel_table + b*HID;            Wb = W_rt;          out = relP + b*D; }
    else             { tbl = time_table + (b-NUM_REL)*HID; Wb = W_rt + HID*D;  out = timP + (b-NUM_REL)*D; }
    float acc = 0.f;
    #pragma unroll
    for (int k = 0; k < HID; ++k) acc += tbl[k] * Wb[k*D + j];
    out[j] = acc;
}

// ---------------------------------------------------------------------------
// k_wpack: pre-pack W13^T and W2^T into MFMA A-frag order, bf16.
// ---------------------------------------------------------------------------
__global__ __launch_bounds__(256) void k_wpack(
        const float* __restrict__ W_fc,
        unsigned short* __restrict__ Wpk13, unsigned short* __restrict__ Wpk2)
{
    int id = blockIdx.x*256 + threadIdx.x;
    if (id < 4096) {                 // W13 frags
        int mt = id >> 8;            // 0..15
        int s  = (id >> 6) & 3;
        int l  = id & 63;
        int m  = mt*16 + (l & 15);   // output col 0..255
        int kb = s*32 + (l >> 4)*8;
        unsigned short* dst = Wpk13 + ((size_t)(mt*4 + s)*64 + l)*8;
        #pragma unroll
        for (int j = 0; j < 8; ++j) {
            int k = kb + j;
            float v = (m < D) ? W_fc[(size_t)k*D + m]
                              : W_fc[(size_t)(256 + k)*D + (m - D)];
            dst[j] = (unsigned short)bf_rne(v);
        }
    } else if (id < 6144) {          // W2 frags
        int id2 = id - 4096;
        int mt = id2 >> 8;           // 0..7
        int s  = (id2 >> 6) & 3;
        int l  = id2 & 63;
        int m  = mt*16 + (l & 15);
        int kb = s*32 + (l >> 4)*8;
        unsigned short* dst = Wpk2 + ((size_t)(mt*4 + s)*64 + l)*8;
        #pragma unroll
        for (int j = 0; j < 8; ++j) {
            int k = kb + j;
            dst[j] = (unsigned short)bf_rne(W_fc[(size_t)(D + k)*D + m]);
        }
    }
}

// ---------------------------------------------------------------------------
// K2 (MFMA): xW13bf[node][256] = bf16( x[node] @ [W1|W3] ), computed as C^T.
// ---------------------------------------------------------------------------
__global__ __launch_bounds__(256, 3) void k_xw(
        const float* __restrict__ x, const unsigned short* __restrict__ Wpk13,
        unsigned short* __restrict__ xW13bf, int n_nodes)
{
    __shared__ __align__(16) unsigned short Xs[64*XPAD];   // 17.4 KB
    int t = threadIdx.x;
    int nodeBase = blockIdx.x*64;
    {   // stage X tile (fp32 -> bf16), 4 threads per node row
        int row = t >> 2;
        int k0  = (t & 3)*32;
        int node = nodeBase + row;
        unsigned short* dst = Xs + row*XPAD + k0;
        if (node < n_nodes) {
            const float4* src = (const float4*)(x + (size_t)node*D + k0);
            #pragma unroll
            for (int g = 0; g < 8; ++g) {
                float4 v = src[g];
                *(uint2*)(dst + g*4) = make_uint2(pk2(v.x, v.y), pk2(v.z, v.w));
            }
        } else {
            #pragma unroll
            for (int g = 0; g < 8; ++g)
                *(uint2*)(dst + g*4) = make_uint2(0u, 0u);
        }
    }
    __syncthreads();

    int w = t >> 6, l = t & 63;
    int li = l & 15, q = l >> 4;

    f32x4 acc[4][4];
    #pragma unroll
    for (int mi = 0; mi < 4; ++mi)
        #pragma unroll
        for (int ni = 0; ni < 4; ++ni) acc[mi][ni] = (f32x4){0.f,0.f,0.f,0.f};

    #pragma unroll
    for (int s = 0; s < 4; ++s) {
        short8 af[4], bf[4];
        #pragma unroll
        for (int mi = 0; mi < 4; ++mi) {
            int mt = w*4 + mi;
            af[mi] = *(const short8*)(Wpk13 + ((size_t)(mt*4 + s)*64 + l)*8);
        }
        #pragma unroll
        for (int ni = 0; ni < 4; ++ni)
            bf[ni] = *(const short8*)(Xs + (ni*16 + li)*XPAD + s*32 + q*8);
        #pragma unroll
        for (int mi = 0; mi < 4; ++mi)
            #pragma unroll
            for (int ni = 0; ni < 4; ++ni)
                acc[mi][ni] = __builtin_amdgcn_mfma_f32_16x16x32_bf16(
                                  af[mi], bf[ni], acc[mi][ni], 0, 0, 0);
    }
    #pragma unroll
    for (int ni = 0; ni < 4; ++ni) {
        int node = nodeBase + ni*16 + li;
        if (node >= n_nodes) continue;
        #pragma unroll
        for (int mi = 0; mi < 4; ++mi) {
            int col = w*64 + mi*16 + q*4;
            *(uint2*)(xW13bf + (size_t)node*256 + col) =
                make_uint2(pk2(acc[mi][ni][0], acc[mi][ni][1]),
                           pk2(acc[mi][ni][2], acc[mi][ni][3]));
        }
    }
}

// ---------------------------------------------------------------------------
// K3 (MFMA): T2bf[c][128] = bf16( lrelu(relP[r]+timP[t]+b_rt) @ W2 ), as C^T.
// ---------------------------------------------------------------------------
__global__ __launch_bounds__(256, 3) void k_t2(
        const float* __restrict__ relP, const float* __restrict__ timP,
        const float* __restrict__ b_rt, const unsigned short* __restrict__ Wpk2,
        unsigned short* __restrict__ T2bf)
{
    __shared__ __align__(16) unsigned short Hs[128*XPAD];  // 34.8 KB
    int t = threadIdx.x;
    int cBase = blockIdx.x*128;
    {   // stage H tile: compute lrelu(relP+timP+b) -> bf16, 2 threads per row
        int r  = t >> 1;
        int hk = (t & 1)*64;
        int combo = cBase + r;
        if (combo >= NCOMB) combo = NCOMB - 1;
        int rr = combo / NUM_TS;
        int tt = combo - rr*NUM_TS;
        const float4* rv4 = (const float4*)(relP + (size_t)rr*D + hk);
        const float4* tv4 = (const float4*)(timP + (size_t)tt*D + hk);
        const float4* bv4 = (const float4*)(b_rt + hk);
        unsigned short* dst = Hs + r*XPAD + hk;
        #pragma unroll
        for (int g = 0; g < 16; ++g) {
            float4 rv = rv4[g], tv = tv4[g], bv = bv4[g];
            float v0 = lrelu(rv.x+tv.x+bv.x), v1 = lrelu(rv.y+tv.y+bv.y);
            float v2 = lrelu(rv.z+tv.z+bv.z), v3 = lrelu(rv.w+tv.w+bv.w);
            *(uint2*)(dst + g*4) = make_uint2(pk2(v0,v1), pk2(v2,v3));
        }
    }
    __syncthreads();

    int w = t >> 6, l = t & 63;
    int li = l & 15, q = l >> 4;
    int mb = (w & 1)*4;        // m-tile base: cols (mb+mi)*16
    int nb = (w >> 1)*64;      // combo base within block

    f32x4 acc[4][4];
    #pragma unroll
    for (int mi = 0; mi < 4; ++mi)
        #pragma unroll
        for (int ni = 0; ni < 4; ++ni) acc[mi][ni] = (f32x4){0.f,0.f,0.f,0.f};

    #pragma unroll
    for (int s = 0; s < 4; ++s) {
        short8 af[4], bf[4];
        #pragma unroll
        for (int mi = 0; mi < 4; ++mi)
            af[mi] = *(const short8*)(Wpk2 + ((size_t)((mb+mi)*4 + s)*64 + l)*8);
        #pragma unroll
        for (int ni = 0; ni < 4; ++ni)
            bf[ni] = *(const short8*)(Hs + (nb + ni*16 + li)*XPAD + s*32 + q*8);
        #pragma unroll
        for (int mi = 0; mi < 4; ++mi)
            #pragma unroll
            for (int ni = 0; ni < 4; ++ni)
                acc[mi][ni] = __builtin_amdgcn_mfma_f32_16x16x32_bf16(
                                  af[mi], bf[ni], acc[mi][ni], 0, 0, 0);
    }
    #pragma unroll
    for (int ni = 0; ni < 4; ++ni) {
        int combo = cBase + nb + ni*16 + li;
        if (combo >= NCOMB) continue;
        #pragma unroll
        for (int mi = 0; mi < 4; ++mi) {
            int col = (mb + mi)*16 + q*4;
            *(uint2*)(T2bf + (size_t)combo*D + col) =
                make_uint2(pk2(acc[mi][ni][0], acc[mi][ni][1]),
                           pk2(acc[mi][ni][2], acc[mi][ni][3]));
        }
    }
}

// ---------------------------------------------------------------------------
// CSR build: degree count -> block scan -> scatter {src, combo} per dst.
// ---------------------------------------------------------------------------
__global__ __launch_bounds__(256) void k_count(
        const int* __restrict__ edges, int* __restrict__ deg, int n_edges)
{
    int e = blockIdx.x*256 + threadIdx.x;
    if (e >= n_edges) return;
    atomicAdd(&deg[((const int4*)edges)[e].y], 1);
}

__global__ __launch_bounds__(256) void k_scan1(
        const int* __restrict__ deg, int* __restrict__ inc,
        int* __restrict__ blkSum, int n)
{
    __shared__ int s[256];
    int i = blockIdx.x*256 + threadIdx.x;
    s[threadIdx.x] = (i < n) ? deg[i] : 0;
    __syncthreads();
    #pragma unroll
    for (int off = 1; off < 256; off <<= 1) {
        int v = (threadIdx.x >= off) ? s[threadIdx.x - off] : 0;
        __syncthreads();
        s[threadIdx.x] += v;
        __syncthreads();
    }
    if (i < n) inc[i] = s[threadIdx.x];
    if (threadIdx.x == 255) blkSum[blockIdx.x] = s[255];
}

__global__ __launch_bounds__(256) void k_scan2(int* __restrict__ blkSum, int nblk)
{
    __shared__ int s[256];
    s[threadIdx.x] = (threadIdx.x < nblk) ? blkSum[threadIdx.x] : 0;
    __syncthreads();
    #pragma unroll
    for (int off = 1; off < 256; off <<= 1) {
        int v = (threadIdx.x >= off) ? s[threadIdx.x - off] : 0;
        __syncthreads();
        s[threadIdx.x] += v;
        __syncthreads();
    }
    if (threadIdx.x < nblk) blkSum[threadIdx.x] = s[threadIdx.x];
}

__global__ __launch_bounds__(256) void k_scan3(
        const int* __restrict__ inc, const int* __restrict__ blkSum,
        const int* __restrict__ deg, int* __restrict__ rowPtr,
        int* __restrict__ wIdx, int n)
{
    int i = blockIdx.x*256 + threadIdx.x;
    if (i >= n) return;
    int carry = (blockIdx.x > 0) ? blkSum[blockIdx.x - 1] : 0;
    int incl = inc[i] + carry;
    rowPtr[i+1] = incl;
    wIdx[i] = incl - deg[i];
    if (i == 0) rowPtr[0] = 0;
}

__global__ __launch_bounds__(256) void k_scatter(
        const int* __restrict__ edges, int* __restrict__ wIdx,
        int2* __restrict__ ebuf, int n_edges)
{
    int e = blockIdx.x*256 + threadIdx.x;
    if (e >= n_edges) return;
    int4 ed = ((const int4*)edges)[e];
    int p = atomicAdd(&wIdx[ed.y], 1);
    ebuf[p] = make_int2(ed.x, ed.z*NUM_TS + ed.w);
}

// ---------------------------------------------------------------------------
// K4: aggregation. One wave per dst node, 2 cols per lane.
// Edge loop unrolled x4 with independent accumulators -> 8 gathers in flight.
// ---------------------------------------------------------------------------
__global__ __launch_bounds__(256) void k_agg(
        const int* __restrict__ rowPtr, const int2* __restrict__ ebuf,
        const unsigned short* __restrict__ xW13bf,
        const unsigned short* __restrict__ T2bf,
        const float* __restrict__ b_fc,
        float* __restrict__ out, int n_nodes)
{
    int node = blockIdx.x*4 + (threadIdx.x >> 6);
    int lane = threadIdx.x & 63;
    if (node >= n_nodes) return;
    int beg = rowPtr[node], end = rowPtr[node+1];

    float2 bb = *(const float2*)&b_fc[2*lane];
    unsigned xw3 = *(const unsigned*)&xW13bf[(size_t)node*256 + 128 + 2*lane];
    float base0 = bf_lo(xw3) + bb.x;
    float base1 = bf_hi(xw3) + bb.y;

    float a0 = 0.f, a1 = 0.f, b0 = 0.f, b1 = 0.f;
    float c0 = 0.f, c1 = 0.f, d0 = 0.f, d1 = 0.f;
    int e = beg;
    for (; e + 4 <= end; e += 4) {
        int2 e0 = ebuf[e+0];
        int2 e1 = ebuf[e+1];
        int2 e2 = ebuf[e+2];
        int2 e3 = ebuf[e+3];
        unsigned s0 = *(const unsigned*)&xW13bf[(size_t)e0.x*256 + 2*lane];
        unsigned t0 = *(const unsigned*)&T2bf  [(size_t)e0.y*D   + 2*lane];
        unsigned s1 = *(const unsigned*)&xW13bf[(size_t)e1.x*256 + 2*lane];
        unsigned t1 = *(const unsigned*)&T2bf  [(size_t)e1.y*D   + 2*lane];
        unsigned s2 = *(const unsigned*)&xW13bf[(size_t)e2.x*256 + 2*lane];
        unsigned t2 = *(const unsigned*)&T2bf  [(size_t)e2.y*D   + 2*lane];
        unsigned s3 = *(const unsigned*)&xW13bf[(size_t)e3.x*256 + 2*lane];
        unsigned t3 = *(const unsigned*)&T2bf  [(size_t)e3.y*D   + 2*lane];
        a0 += lrelu(bf_lo(s0) + bf_lo(t0) + base0);
        a1 += lrelu(bf_hi(s0) + bf_hi(t0) + base1);
        b0 += lrelu(bf_lo(s1) + bf_lo(t1) + base0);
        b1 += lrelu(bf_hi(s1) + bf_hi(t1) + base1);
        c0 += lrelu(bf_lo(s2) + bf_lo(t2) + base0);
        c1 += lrelu(bf_hi(s2) + bf_hi(t2) + base1);
        d0 += lrelu(bf_lo(s3) + bf_lo(t3) + base0);
        d1 += lrelu(bf_hi(s3) + bf_hi(t3) + base1);
    }
    for (; e < end; ++e) {
        int2 ed = ebuf[e];
        unsigned u1 = *(const unsigned*)&xW13bf[(size_t)ed.x*256 + 2*lane];
        unsigned u2 = *(const unsigned*)&T2bf  [(size_t)ed.y*D   + 2*lane];
        a0 += lrelu(bf_lo(u1) + bf_lo(u2) + base0);
        a1 += lrelu(bf_hi(u1) + bf_hi(u2) + base1);
    }
    float s0 = (a0 + b0) + (c0 + d0);
    float s1 = (a1 + b1) + (c1 + d1);
    float inv = 1.f / fmaxf((float)(end - beg), 1.f);
    *(float2*)&out[(size_t)node*D + 2*lane] = make_float2(s0*inv, s1*inv);
}

// ---------------------------------------------------------------------------
extern "C" void kernel_launch(void* const* d_in, const int* in_sizes, int n_in,
                              void* d_out, int out_size, void* d_ws, size_t ws_size,
                              hipStream_t stream)
{
    const float* x          = (const float*)d_in[0];
    const float* rel_table  = (const float*)d_in[1];
    const float* time_table = (const float*)d_in[2];
    const float* W_rt       = (const float*)d_in[3];
    const float* b_rt       = (const float*)d_in[4];
    const float* W_fc       = (const float*)d_in[5];
    const float* b_fc       = (const float*)d_in[6];
    const int*   edges      = (const int*)d_in[7];

    int n_nodes = in_sizes[0] / D;   // 50000
    int n_edges = in_sizes[7] / 4;   // 400000
    int nblk    = (n_nodes + 255) / 256;

    char* ws = (char*)d_ws;
    size_t off = 0;
    auto alloc = [&](size_t bytes) -> void* {
        void* p = ws + off; off += (bytes + 255) & ~(size_t)255; return p;
    };
    unsigned short* xW13bf = (unsigned short*)alloc((size_t)n_nodes * 256 * 2); // 25.6 MB
    unsigned short* T2bf   = (unsigned short*)alloc((size_t)NCOMB * D * 2);     // 21.5 MB
    unsigned short* Wpk13  = (unsigned short*)alloc((size_t)16*4*64*8 * 2);     // 64 KB
    unsigned short* Wpk2   = (unsigned short*)alloc((size_t)8*4*64*8 * 2);      // 32 KB
    float* relP   = (float*)alloc((size_t)NUM_REL * D * sizeof(float));
    float* timP   = (float*)alloc((size_t)NUM_TS * D * sizeof(float));
    int*   deg    = (int*)alloc((size_t)n_nodes * sizeof(int));
    int*   inc    = (int*)alloc((size_t)n_nodes * sizeof(int));
    int*   blkSum = (int*)alloc((size_t)nblk * sizeof(int));
    int*   rowPtr = (int*)alloc((size_t)(n_nodes + 1) * sizeof(int));
    int*   wIdx   = (int*)alloc((size_t)n_nodes * sizeof(int));
    int2*  ebuf   = (int2*)alloc((size_t)n_edges * sizeof(int2));               // 3.2 MB
    if (off > ws_size)
        fprintf(stderr, "kernel_launch: workspace too small: need %zu, have %zu\n", off, ws_size);

    hipMemsetAsync(deg, 0, (size_t)n_nodes * sizeof(int), stream);

    k_parts  <<<NUM_REL + NUM_TS, 128, 0, stream>>>(rel_table, time_table, W_rt, relP, timP);
    k_wpack  <<<24, 256, 0, stream>>>(W_fc, Wpk13, Wpk2);
    k_xw     <<<(n_nodes + 63)/64, 256, 0, stream>>>(x, Wpk13, xW13bf, n_nodes);
    k_t2     <<<(NCOMB + 127)/128, 256, 0, stream>>>(relP, timP, b_rt, Wpk2, T2bf);
    k_count  <<<(n_edges + 255)/256, 256, 0, stream>>>(edges, deg, n_edges);
    k_scan1  <<<nblk, 256, 0, stream>>>(deg, inc, blkSum, n_nodes);
    k_scan2  <<<1, 256, 0, stream>>>(blkSum, nblk);
    k_scan3  <<<nblk, 256, 0, stream>>>(inc, blkSum, deg, rowPtr, wIdx, n_nodes);
    k_scatter<<<(n_edges + 255)/256, 256, 0, stream>>>(edges, wIdx, ebuf, n_edges);
    k_agg    <<<(n_nodes + 3)/4, 256, 0, stream>>>(rowPtr, ebuf, xW13bf, T2bf, b_fc,
                                                   (float*)d_out, n_nodes);
}